// Round 2
// baseline (391.988 us; speedup 1.0000x reference)
//
#include <hip/hip_runtime.h>

// HeteroLinear fused forward on gfx950: out[i] = x[i] @ W[tv[i]] + b[tv[i]]
// N=131072, IN=OUT=256, T=8, tv sorted. Memory-bound (min ~258 MB HBM).
// R2: persistent blocks (512 = 2/CU), 8 waves, wave tile 64x32, T14
// async-STAGE pipeline (issue next x-tile loads before computing current),
// bf16 MFMA 16x16x32, XOR-swizzled LDS A-tile, coalesced LDS-transpose prep.

#define NROWS 131072
#define KD 256
#define ND 256
#define NTILES (NROWS / 64)      // 2048
#define TPB 4                    // tiles per block
#define GRID_MAIN (NTILES / TPB) // 512

typedef __attribute__((ext_vector_type(8))) short short8;
typedef __attribute__((ext_vector_type(4))) short short4v;
typedef __attribute__((ext_vector_type(4))) float f32x4;
typedef __attribute__((ext_vector_type(4))) float flt4;

__device__ inline unsigned short f2bf(float f) {
    unsigned int u = __float_as_uint(f);
    u += 0x7FFFu + ((u >> 16) & 1u);   // RNE
    return (unsigned short)(u >> 16);
}

// ---- weight prep: wT[t][n][k] = bf16(w[t][k][n]), coalesced via LDS ----
// grid = 32 blocks: (t = bid>>2, k-chunk of 64 = bid&3), 256 threads.
__global__ __launch_bounds__(256) void prep_weights(const float* __restrict__ w,
                                                    unsigned short* __restrict__ wT) {
    __shared__ unsigned short L[64][264];   // [k-row][n], padded: 528B row stride
    const int t  = blockIdx.x >> 2;
    const int k0 = (blockIdx.x & 3) * 64;
    const int tid = threadIdx.x;

    // load 64 k-rows x 256 n, coalesced float4, cvt to bf16 into LDS
    #pragma unroll
    for (int i = 0; i < 16; ++i) {
        int idx = i * 256 + tid;          // 0..4095 float4s
        int kr  = idx >> 6;               // 0..63
        int nq  = idx & 63;               // n = nq*4
        const flt4* src = (const flt4*)(w + ((size_t)t * 256 + k0 + kr) * 256);
        flt4 v = src[nq];
        #pragma unroll
        for (int j = 0; j < 4; ++j) L[kr][nq * 4 + j] = f2bf(v[j]);
    }
    __syncthreads();

    // write transposed: 2048 slots = 256 n x 8 k-groups; 16B coalesced stores
    #pragma unroll
    for (int i = 0; i < 8; ++i) {
        int s  = i * 256 + tid;
        int n  = s >> 3;
        int kg = s & 7;                   // k sub-offset kg*8
        short8 v;
        #pragma unroll
        for (int j = 0; j < 8; ++j) v[j] = (short)L[kg * 8 + j][n];
        *(short8*)(wT + ((size_t)t * 256 + n) * 256 + k0 + kg * 8) = v;
    }
}

// ---- main GEMM ----
__global__ __launch_bounds__(512, 4) void hetero_gemm(
        const float* __restrict__ x, const int* __restrict__ tv,
        const unsigned short* __restrict__ wT, const float* __restrict__ bias,
        float* __restrict__ out) {
    __shared__ short A[64 * 256];   // bf16, swizzled: half-idx ^= (row&7)<<3
    __shared__ int types[64];

    const int tid  = threadIdx.x;
    const int lane = tid & 63;
    const int wv   = tid >> 6;            // wave 0..7 -> cols wv*32..wv*32+31
    const int cl   = lane & 15;
    const int kg   = lane >> 4;
    const int tile0 = blockIdx.x * TPB;

    flt4 xr[8];
    int  tyr = 0;

    // prologue: load tile0 into regs
    {
        const flt4* xv = (const flt4*)(x + (size_t)tile0 * 64 * KD);
        #pragma unroll
        for (int i = 0; i < 8; ++i) xr[i] = xv[i * 512 + tid];
        if (tid < 64) tyr = tv[tile0 * 64 + tid];
    }
    // stage tile0 into LDS
    #pragma unroll
    for (int i = 0; i < 8; ++i) {
        int idx = i * 512 + tid;          // 0..4095 float4s (64 rows x 64/row)
        int row = idx >> 6;
        int kq  = idx & 63;
        short4v s;
        #pragma unroll
        for (int j = 0; j < 4; ++j) s[j] = (short)f2bf(xr[i][j]);
        int h = (row << 8) + (kq << 2);
        h ^= (row & 7) << 3;
        *(short4v*)&A[h] = s;
    }
    if (tid < 64) types[tid] = tyr;
    __syncthreads();

    for (int it = 0; it < TPB; ++it) {
        const int r0 = (tile0 + it) * 64;

        // T14: issue next tile's global loads NOW; they ride under compute
        if (it + 1 < TPB) {
            const flt4* xv = (const flt4*)(x + (size_t)(r0 + 64) * KD);
            #pragma unroll
            for (int i = 0; i < 8; ++i) xr[i] = xv[i * 512 + tid];
            if (tid < 64) tyr = tv[r0 + 64 + tid];
        }

        const int tmin = types[0];        // sorted -> min/max at tile ends
        const int tmax = types[63];

        for (int t = tmin; t <= tmax; ++t) {
            const unsigned short* Bt = wT + (size_t)t * (KD * ND);
            float bv0 = bias[t * ND + wv * 32 + cl];
            float bv1 = bias[t * ND + wv * 32 + 16 + cl];

            f32x4 zero = {0.f, 0.f, 0.f, 0.f};
            f32x4 acc[4][2];
            #pragma unroll
            for (int m = 0; m < 4; ++m) { acc[m][0] = zero; acc[m][1] = zero; }

            #pragma unroll
            for (int ks = 0; ks < 8; ++ks) {
                const int k0 = ks * 32;
                short8 a[4], b[2];
                #pragma unroll
                for (int m = 0; m < 4; ++m) {
                    int row = m * 16 + cl;
                    int h = (row << 8) + k0 + kg * 8;
                    h ^= (row & 7) << 3;
                    a[m] = *(const short8*)&A[h];
                }
                #pragma unroll
                for (int n = 0; n < 2; ++n) {
                    int col = wv * 32 + n * 16 + cl;
                    b[n] = *(const short8*)(Bt + col * KD + k0 + kg * 8);
                }
                #pragma unroll
                for (int m = 0; m < 4; ++m) {
                    acc[m][0] = __builtin_amdgcn_mfma_f32_16x16x32_bf16(a[m], b[0], acc[m][0], 0, 0, 0);
                    acc[m][1] = __builtin_amdgcn_mfma_f32_16x16x32_bf16(a[m], b[1], acc[m][1], 0, 0, 0);
                }
            }

            // epilogue: bias + predicated store (row type == t)
            #pragma unroll
            for (int m = 0; m < 4; ++m) {
                int rbase = m * 16 + kg * 4;
                #pragma unroll
                for (int j = 0; j < 4; ++j) {
                    int r = rbase + j;
                    if (types[r] == t) {
                        float* orow = out + (size_t)(r0 + r) * ND + wv * 32 + cl;
                        orow[0]  = acc[m][0][j] + bv0;
                        orow[16] = acc[m][1][j] + bv1;
                    }
                }
            }
        }

        __syncthreads();                  // all waves done reading A/types
        if (it + 1 < TPB) {               // write prefetched tile into LDS
            #pragma unroll
            for (int i = 0; i < 8; ++i) {
                int idx = i * 512 + tid;
                int row = idx >> 6;
                int kq  = idx & 63;
                short4v s;
                #pragma unroll
                for (int j = 0; j < 4; ++j) s[j] = (short)f2bf(xr[i][j]);
                int h = (row << 8) + (kq << 2);
                h ^= (row & 7) << 3;
                *(short4v*)&A[h] = s;
            }
            if (tid < 64) types[tid] = tyr;
            __syncthreads();
        }
    }
}

extern "C" void kernel_launch(void* const* d_in, const int* in_sizes, int n_in,
                              void* d_out, int out_size, void* d_ws, size_t ws_size,
                              hipStream_t stream) {
    const float* x    = (const float*)d_in[0];
    const int*   tv   = (const int*)d_in[1];
    const float* w    = (const float*)d_in[2];
    const float* bias = (const float*)d_in[3];
    float* out = (float*)d_out;
    unsigned short* wT = (unsigned short*)d_ws;   // 8*256*256*2 = 1 MiB

    prep_weights<<<dim3(32), dim3(256), 0, stream>>>(w, wT);
    hetero_gemm<<<dim3(GRID_MAIN), dim3(512), 0, stream>>>(x, tv, wT, bias, out);
}

// Round 3
// 107.039 us; speedup vs baseline: 3.6621x; 3.6621x over previous
//
#include <hip/hip_runtime.h>

// HeteroLinear fused forward on gfx950: out[i] = x[i] @ W[tv[i]] + b[tv[i]]
// N=131072, IN=OUT=256, T=8, tv sorted. Memory-bound: floor ~258 MB -> ~41 us.
// R3: persistent blocks, double-buffered fp32 LDS x-tile staged via
// global_load_lds (async DMA, zero VGPR cost), prefetch next tile before
// computing current. bf16 cvt at fragment-read time. Source-side XOR swizzle
// (rule 21) for balanced ds_read_b128. Wave tile 32x64 -> acc 32 VGPR.

#define NROWS 131072
#define KD 256
#define ND 256
#define RT 32                     // rows per tile
#define NTILES (NROWS / RT)       // 4096
#define TPB 8                     // tiles per block
#define GRID_MAIN (NTILES / TPB)  // 512 blocks = 2/CU (LDS-limited)

typedef __attribute__((ext_vector_type(8))) short short8;
typedef __attribute__((ext_vector_type(4))) float f32x4;
typedef __attribute__((ext_vector_type(4))) float flt4;

typedef __attribute__((address_space(3))) unsigned int lds_u32_t;
typedef __attribute__((address_space(1))) unsigned int glb_u32_t;

__device__ inline unsigned short f2bf(float f) {
    unsigned int u = __float_as_uint(f);
    u += 0x7FFFu + ((u >> 16) & 1u);   // RNE
    return (unsigned short)(u >> 16);
}

// ---- weight prep: wT[t][n][k] = bf16(w[t][k][n]) ----
// grid = 256 blocks: t = bid>>5, k-chunk of 8 rows = bid&31. 256 threads.
__global__ __launch_bounds__(256) void prep_weights(const float* __restrict__ w,
                                                    unsigned short* __restrict__ wT) {
    __shared__ unsigned short L[8][264];
    const int t  = blockIdx.x >> 5;
    const int k0 = (blockIdx.x & 31) * 8;
    const int tid = threadIdx.x;

    #pragma unroll
    for (int i = 0; i < 2; ++i) {
        int idx = i * 256 + tid;          // 0..511 float4s (8 rows x 64)
        int kr  = idx >> 6;
        int nq  = idx & 63;
        const flt4* src = (const flt4*)(w + ((size_t)t * 256 + k0 + kr) * 256);
        flt4 v = src[nq];
        #pragma unroll
        for (int j = 0; j < 4; ++j) L[kr][nq * 4 + j] = f2bf(v[j]);
    }
    __syncthreads();

    int n = tid;                          // 0..255
    short8 v;
    #pragma unroll
    for (int j = 0; j < 8; ++j) v[j] = (short)L[j][n];
    *(short8*)(wT + ((size_t)t * 256 + n) * 256 + k0) = v;
}

// ---- main GEMM ----
__global__ __launch_bounds__(256) void hetero_gemm(
        const float* __restrict__ x, const int* __restrict__ tv,
        const unsigned short* __restrict__ wT, const float* __restrict__ bias,
        float* __restrict__ out) {
    __shared__ float A[2][RT * 256];      // fp32 x-tile, double-buffered
    __shared__ int types[2][RT];

    const int tid  = threadIdx.x;
    const int lane = tid & 63;
    const int wv   = tid >> 6;            // wave 0..3 -> cols wv*64..+63
    const int cl   = lane & 15;
    const int kg   = lane >> 4;
    const int tile0 = blockIdx.x * TPB;

    // ---------- stage: issue async DMA for tile -> buf ----------
    auto stage = [&](int buf, int tile) {
        const int r0 = tile * RT;
        // wave wv stages rows wv*8..wv*8+7; one global_load_lds = one row (1KB)
        #pragma unroll
        for (int r8 = 0; r8 < 8; ++r8) {
            int r = wv * 8 + r8;
            // source-side swizzle: LDS group g holds x float4-group g^(r&7)
            const float* gp = x + (size_t)(r0 + r) * KD + ((lane ^ (r & 7)) << 2);
            __builtin_amdgcn_global_load_lds((const glb_u32_t*)gp,
                                             (lds_u32_t*)&A[buf][r * 256],
                                             16, 0, 0);
        }
        if (tid < RT) types[buf][tid] = tv[r0 + tid];
    };

    // ---------- compute on buf ----------
    auto compute = [&](int buf, int tile) {
        const int r0 = tile * RT;
        const int tmin = types[buf][0];
        const int tmax = types[buf][RT - 1];
        const f32x4* Af = (const f32x4*)&A[buf][0];
        const int s = cl & 7;

        for (int t = tmin; t <= tmax; ++t) {
            const unsigned short* Bt = wT + (size_t)t * (KD * ND);
            float bv[4];
            #pragma unroll
            for (int n = 0; n < 4; ++n)
                bv[n] = bias[t * ND + wv * 64 + n * 16 + cl];

            f32x4 zero = {0.f, 0.f, 0.f, 0.f};
            f32x4 acc[2][4];
            #pragma unroll
            for (int m = 0; m < 2; ++m)
                #pragma unroll
                for (int n = 0; n < 4; ++n) acc[m][n] = zero;

            #pragma unroll
            for (int ks = 0; ks < 8; ++ks) {
                short8 a[2];
                #pragma unroll
                for (int m = 0; m < 2; ++m) {
                    int r  = m * 16 + cl;
                    int G0 = ks * 8 + kg * 2;          // even float4-group
                    f32x4 v0 = Af[r * 64 + (G0 ^ s)];
                    f32x4 v1 = Af[r * 64 + ((G0 + 1) ^ s)];
                    short8 t8;
                    #pragma unroll
                    for (int j = 0; j < 4; ++j) {
                        t8[j]     = (short)f2bf(v0[j]);
                        t8[4 + j] = (short)f2bf(v1[j]);
                    }
                    a[m] = t8;
                }
                short8 b[4];
                #pragma unroll
                for (int n = 0; n < 4; ++n)
                    b[n] = *(const short8*)(Bt + (size_t)(wv * 64 + n * 16 + cl) * KD
                                            + ks * 32 + kg * 8);
                #pragma unroll
                for (int m = 0; m < 2; ++m)
                    #pragma unroll
                    for (int n = 0; n < 4; ++n)
                        acc[m][n] = __builtin_amdgcn_mfma_f32_16x16x32_bf16(
                            a[m], b[n], acc[m][n], 0, 0, 0);
            }

            // epilogue: bias + predicated store
            #pragma unroll
            for (int m = 0; m < 2; ++m) {
                #pragma unroll
                for (int j = 0; j < 4; ++j) {
                    int r = m * 16 + kg * 4 + j;
                    if (types[buf][r] == t) {
                        float* orow = out + (size_t)(r0 + r) * ND + wv * 64 + cl;
                        #pragma unroll
                        for (int n = 0; n < 4; ++n) orow[n * 16] = acc[m][n][j] + bv[n];
                    }
                }
            }
        }
    };

    stage(0, tile0);
    __syncthreads();                      // drains DMA: buf0 ready

    for (int it = 0; it < TPB; ++it) {
        if (it + 1 < TPB) stage((it + 1) & 1, tile0 + it + 1);  // async prefetch
        compute(it & 1, tile0 + it);
        __syncthreads();                  // prefetch done + all reads of cur buf done
    }
}

extern "C" void kernel_launch(void* const* d_in, const int* in_sizes, int n_in,
                              void* d_out, int out_size, void* d_ws, size_t ws_size,
                              hipStream_t stream) {
    const float* x    = (const float*)d_in[0];
    const int*   tv   = (const int*)d_in[1];
    const float* w    = (const float*)d_in[2];
    const float* bias = (const float*)d_in[3];
    float* out = (float*)d_out;
    unsigned short* wT = (unsigned short*)d_ws;   // 8*256*256*2 = 1 MiB

    prep_weights<<<dim3(256), dim3(256), 0, stream>>>(w, wT);
    hetero_gemm<<<dim3(GRID_MAIN), dim3(256), 0, stream>>>(x, tv, wT, bias, out);
}